// Round 5
// baseline (393.379 us; speedup 1.0000x reference)
//
#include <hip/hip_runtime.h>
#include <hip/hip_bf16.h>

#define BB 8
#define FF 64
#define NPTS 100000
#define RES 32
#define R3 (RES*RES*RES)
#define EPSV 1e-6f
#define SEGS (BB*R3)            // 262144 voxel segments (2^18)
#define NPTS_TOT (BB*NPTS)      // 800000 points (= sorted rows)
#define NWIN (NPTS_TOT/64)      // 12500 gather windows (exact)

static constexpr size_t GRID_ELEMS = (size_t)BB * FF * R3;   // 16,777,216

__device__ __forceinline__ float bf16f(ushort u) {
    return __uint_as_float((unsigned)u << 16);
}
__device__ __forceinline__ ushort f2bf(float f) {
    __hip_bfloat16 h = __float2bfloat16(f);
    return *reinterpret_cast<ushort*>(&h);
}

// ---------------- Kernel A: per-batch coordinate sums ----------------
#define NB_STAT 64
__global__ void k_sum_coords(const float* __restrict__ coords, float* __restrict__ sums) {
    int b = blockIdx.x / NB_STAT;
    int chunk = blockIdx.x % NB_STAT;
    const float* cb = coords + (size_t)b * 3 * NPTS;
    float sx = 0.f, sy = 0.f, sz = 0.f;
    for (int i = chunk * blockDim.x + threadIdx.x; i < NPTS; i += NB_STAT * blockDim.x) {
        sx += cb[i];
        sy += cb[NPTS + i];
        sz += cb[2 * NPTS + i];
    }
    for (int off = 32; off; off >>= 1) {
        sx += __shfl_down(sx, off);
        sy += __shfl_down(sy, off);
        sz += __shfl_down(sz, off);
    }
    __shared__ float lsx[4], lsy[4], lsz[4];
    int lane = threadIdx.x & 63, wid = threadIdx.x >> 6;
    if (lane == 0) { lsx[wid] = sx; lsy[wid] = sy; lsz[wid] = sz; }
    __syncthreads();
    if (threadIdx.x == 0) {
        float tx = 0.f, ty = 0.f, tz = 0.f;
        for (int w = 0; w < 4; ++w) { tx += lsx[w]; ty += lsy[w]; tz += lsz[w]; }
        atomicAdd(&sums[b * 3 + 0], tx);
        atomicAdd(&sums[b * 3 + 1], ty);
        atomicAdd(&sums[b * 3 + 2], tz);
    }
}

// ---------------- Kernel B: per-batch max radius ----------------
__global__ void k_radius(const float* __restrict__ coords, const float* __restrict__ sums,
                         int* __restrict__ rad_bits) {
    int b = blockIdx.x / NB_STAT;
    int chunk = blockIdx.x % NB_STAT;
    const float* cb = coords + (size_t)b * 3 * NPTS;
    float mx = sums[b * 3 + 0] / (float)NPTS;
    float my = sums[b * 3 + 1] / (float)NPTS;
    float mz = sums[b * 3 + 2] / (float)NPTS;
    float mval = 0.f;
    for (int i = chunk * blockDim.x + threadIdx.x; i < NPTS; i += NB_STAT * blockDim.x) {
        float x = cb[i] - mx;
        float y = cb[NPTS + i] - my;
        float z = cb[2 * NPTS + i] - mz;
        float nrm = sqrtf(x * x + y * y + z * z);
        mval = fmaxf(mval, nrm);
    }
    for (int off = 32; off; off >>= 1) mval = fmaxf(mval, __shfl_down(mval, off));
    __shared__ float lm[4];
    int lane = threadIdx.x & 63, wid = threadIdx.x >> 6;
    if (lane == 0) lm[wid] = mval;
    __syncthreads();
    if (threadIdx.x == 0) {
        float t = fmaxf(fmaxf(lm[0], lm[1]), fmaxf(lm[2], lm[3]));
        atomicMax(&rad_bits[b], __float_as_int(t));  // norms >= 0: int order == float order
    }
}

// ---------------- Kernel C: per-point voxelize + norm_coords + counts ----------------
__global__ void k_voxelize(const float* __restrict__ coords, const float* __restrict__ sums,
                           const int* __restrict__ rad_bits, float* __restrict__ norm_out,
                           int* __restrict__ voxidx, int* __restrict__ counts) {
    int tid = blockIdx.x * blockDim.x + threadIdx.x;
    if (tid >= NPTS_TOT) return;
    int b = tid / NPTS, n = tid % NPTS;
    const float* cb = coords + (size_t)b * 3 * NPTS;
    float mx = sums[b * 3 + 0] / (float)NPTS;
    float my = sums[b * 3 + 1] / (float)NPTS;
    float mz = sums[b * 3 + 2] / (float)NPTS;
    float r = __int_as_float(rad_bits[b]);
    float d = 2.0f * r + EPSV;
    float x = (cb[n] - mx) / d + 0.5f;
    float y = (cb[NPTS + n] - my) / d + 0.5f;
    float z = (cb[2 * NPTS + n] - mz) / d + 0.5f;
    float nx = fminf(fmaxf(x * (float)RES, 0.0f), (float)(RES - 1));
    float ny = fminf(fmaxf(y * (float)RES, 0.0f), (float)(RES - 1));
    float nz = fminf(fmaxf(z * (float)RES, 0.0f), (float)(RES - 1));
    float* nb_ = norm_out + (size_t)b * 3 * NPTS;
    nb_[n] = nx;
    nb_[NPTS + n] = ny;
    nb_[2 * NPTS + n] = nz;
    int vx = (int)rintf(nx), vy = (int)rintf(ny), vz = (int)rintf(nz);
    int idx = (vx * RES + vy) * RES + vz;
    voxidx[tid] = idx;
    atomicAdd(&counts[b * R3 + idx], 1);
}

// ---------------- Scan: exclusive prefix sum over SEGS counts ----------------
__global__ void k_scan1(const int* __restrict__ counts, int* __restrict__ offsets,
                        int* __restrict__ blocksums) {
    int tid = threadIdx.x, bid = blockIdx.x;
    int base = bid * 1024 + tid * 4;
    int c0 = counts[base], c1 = counts[base + 1], c2 = counts[base + 2], c3 = counts[base + 3];
    int tot = c0 + c1 + c2 + c3;
    int lane = tid & 63, wid = tid >> 6;
    int v = tot;
    for (int off = 1; off < 64; off <<= 1) {
        int u = __shfl_up(v, off);
        if (lane >= off) v += u;
    }
    __shared__ int wtot[4];
    if (lane == 63) wtot[wid] = v;
    __syncthreads();
    int wof = 0;
    for (int w = 0; w < wid; ++w) wof += wtot[w];
    int ex = wof + v - tot;
    offsets[base] = ex;
    offsets[base + 1] = ex + c0;
    offsets[base + 2] = ex + c0 + c1;
    offsets[base + 3] = ex + c0 + c1 + c2;
    if (tid == 0) blocksums[bid] = wtot[0] + wtot[1] + wtot[2] + wtot[3];
}

__global__ void k_scan2(const int* __restrict__ blocksums, int* __restrict__ blockoff) {
    int tid = threadIdx.x;
    int c = blocksums[tid];
    int lane = tid & 63, wid = tid >> 6;
    int v = c;
    for (int off = 1; off < 64; off <<= 1) {
        int u = __shfl_up(v, off);
        if (lane >= off) v += u;
    }
    __shared__ int wtot[4];
    if (lane == 63) wtot[wid] = v;
    __syncthreads();
    int wof = 0;
    for (int w = 0; w < wid; ++w) wof += wtot[w];
    blockoff[tid] = wof + v - c;
}

// ---------------- Kernel C2: fill row->voxel map (sequential runs) ----------------
__global__ void k_fillvox(const int* __restrict__ offsets, const int* __restrict__ blockoff,
                          const int* __restrict__ counts, int* __restrict__ rowvox) {
    int bv = blockIdx.x * 256 + threadIdx.x;
    if (bv >= SEGS) return;
    int off = offsets[bv] + blockoff[bv >> 10];
    int cnt = counts[bv];
    for (int i = 0; i < cnt; ++i) rowvox[off + i] = bv;
}

// ---------------- Kernel C3: perm[dst] = global point row ----------------
__global__ void k_rank(const int* __restrict__ voxidx, const int* __restrict__ offsets,
                       const int* __restrict__ blockoff, int* __restrict__ cursors,
                       int* __restrict__ perm) {
    int g = blockIdx.x * 256 + threadIdx.x;
    if (g >= NPTS_TOT) return;
    int b = g / NPTS;
    int bv = b * R3 + voxidx[g];
    int r = atomicAdd(&cursors[bv], 1);
    perm[offsets[bv] + blockoff[bv >> 10] + r] = g;
}

// ---------------- Kernel D: plain transpose features[B,F,N] -> featT[B*N][64] bf16 ------
__global__ void k_transpose(const float* __restrict__ features, ushort* __restrict__ featT) {
    __shared__ float tileF[64][65];
    int b = blockIdx.y;
    int n0 = blockIdx.x * 64;
    int tid = threadIdx.x, lane = tid & 63, wid = tid >> 6;

    for (int f = wid; f < 64; f += 4) {
        int n = n0 + lane;
        tileF[f][lane] = (n < NPTS) ? features[((size_t)b * FF + f) * NPTS + n] : 0.f;
    }
    __syncthreads();
    size_t g0 = (size_t)b * NPTS + n0;
    int half = lane >> 5;            // 0/1: which of 2 rows this instruction covers
    int f0 = (lane & 31) * 2;        // feature pair
#pragma unroll
    for (int k = 0; k < 8; ++k) {
        int p = wid * 16 + k * 2 + half;
        if (n0 + p < NPTS) {
            unsigned val = (unsigned)f2bf(tileF[f0][p]) | ((unsigned)f2bf(tileF[f0 + 1][p]) << 16);
            ((unsigned*)(featT + ((g0 + p) << 6)))[lane & 31] = val;   // 256B/instr, sequential
        }
    }
}

// ---------------- Kernel E1: linear segmented gather (perm-indirect reads) --------------
// One wave per 64 consecutive sorted rows. Stage window via featT[perm[r]] (128B rows,
// L3-resident) into LDS; detect segment starts from rowvox; sum segments; write bf16 avg.
__global__ void k_gather_lin(const ushort* __restrict__ featT,
                             const int* __restrict__ perm,
                             const int* __restrict__ rowvox,
                             const int* __restrict__ counts,
                             ushort* __restrict__ avgS) {
    __shared__ ushort tile[4][4096];   // 8KB per wave
    int wid = threadIdx.x >> 6, lane = threadIdx.x & 63;
    int w = blockIdx.x * 4 + wid;      // window id [0, NWIN)
    int r0 = w * 64;

    int pr = perm[r0 + lane];          // point row for my sorted row
    int myv = rowvox[r0 + lane];

    // stage: 8 instrs, each reads 8 scattered 128B rows (8 lanes per row, 16B/lane)
    uint4 t[8];
#pragma unroll
    for (int j = 0; j < 8; ++j) {
        int row = j * 8 + (lane >> 3);
        int pi = __shfl(pr, row);
        t[j] = ((const uint4*)(featT + ((size_t)pi << 6)))[lane & 7];
    }
    uint4* ldst = (uint4*)tile[wid];
#pragma unroll
    for (int j = 0; j < 8; ++j) ldst[j * 64 + lane] = t[j];   // contiguous: lane*16B

    int prevv = __shfl_up(myv, 1);
    if (lane == 0) prevv = (r0 > 0) ? rowvox[r0 - 1] : -1;
    unsigned long long flags = __ballot(myv != prevv);

    while (flags) {
        int s = (int)__ffsll(flags) - 1;
        flags &= flags - 1;
        int bv = __shfl(myv, s);
        int cnt = flags ? ((int)__ffsll(flags) - 1 - s) : counts[bv];
        int inwin = min(cnt, 64 - s);
        float acc = 0.f;
        for (int i = 0; i < inwin; ++i) acc += bf16f(tile[wid][(s + i) * 64 + lane]);
        if (cnt > inwin) {  // overhang into following windows (window-final segment only)
            int rem = cnt - inwin;
            for (int i = 0; i < rem; ++i) {
                int pi2 = perm[r0 + 64 + i];                       // uniform: broadcast load
                acc += bf16f(featT[((size_t)pi2 << 6) + lane]);    // coalesced 128B row
            }
        }
        avgS[(size_t)bv * 64 + lane] = f2bf(acc / (float)cnt);
    }
}

// ---------------- Kernel E2: avgS [BV][F] bf16 -> grid [B][F][V] f32 (LDS transpose) ----
__global__ void k_avg2grid(const ushort* __restrict__ avgS, const int* __restrict__ counts,
                           float* __restrict__ grid) {
    __shared__ float tile[64][65];
    int bv0 = blockIdx.x * 64;
    int lane = threadIdx.x & 63, wid = threadIdx.x >> 6;
    for (int p = wid; p < 64; p += 4) {
        int cnt = counts[bv0 + p];
        tile[p][lane] = (cnt > 0) ? bf16f(avgS[(size_t)(bv0 + p) * 64 + lane]) : 0.f;
    }
    __syncthreads();
    int b = bv0 >> 15;          // /R3
    int v0 = bv0 & (R3 - 1);
    for (int f = wid; f < 64; f += 4) {
        grid[((size_t)b * FF + f) * R3 + v0 + lane] = tile[lane][f];
    }
}

// ---------------- Fallback path (atomic scatter), used if ws too small ----------------
__global__ void k_scatter(const float* __restrict__ features, const int* __restrict__ voxidx,
                          float* __restrict__ grid) {
    size_t tid = (size_t)blockIdx.x * blockDim.x + threadIdx.x;
    if (tid >= (size_t)BB * FF * NPTS) return;
    int n = (int)(tid % NPTS);
    int bf = (int)(tid / NPTS);
    int b = bf >> 6;
    int idx = voxidx[(size_t)b * NPTS + n];
    atomicAdd(&grid[(size_t)bf * R3 + idx], features[tid]);
}

__global__ void k_normalize(float* __restrict__ grid, const int* __restrict__ counts) {
    size_t tid = (size_t)blockIdx.x * blockDim.x + threadIdx.x;
    if (tid >= GRID_ELEMS) return;
    int v = (int)(tid % R3);
    int bf = (int)(tid / R3);
    int b = bf >> 6;
    float c = (float)counts[b * R3 + v];
    grid[tid] = grid[tid] / fmaxf(c, 1.0f);
}

extern "C" void kernel_launch(void* const* d_in, const int* in_sizes, int n_in,
                              void* d_out, int out_size, void* d_ws, size_t ws_size,
                              hipStream_t stream) {
    const float* features = (const float*)d_in[0];
    const float* coords = (const float*)d_in[1];
    float* out = (float*)d_out;
    float* grid = out;                      // [B,F,R,R,R]
    float* norm_out = out + GRID_ELEMS;     // [B,3,N]

    char* ws = (char*)d_ws;
    size_t off_sums   = 0;                               // 24 floats
    size_t off_rad    = 128;                             // 8 ints
    size_t off_counts = 256;                             // SEGS ints (1 MB)
    size_t off_offs   = off_counts + (size_t)SEGS * 4;   // 1 MB
    size_t off_curs   = off_offs + (size_t)SEGS * 4;     // 1 MB
    size_t off_bsums  = off_curs + (size_t)SEGS * 4;
    size_t off_boff   = off_bsums + 256 * 4;
    size_t off_vox    = off_boff + 256 * 4;              // 3.2 MB
    size_t off_rowv   = off_vox + (size_t)NPTS_TOT * 4;  // 3.2 MB
    size_t off_perm   = off_rowv + (size_t)NPTS_TOT * 4; // 3.2 MB
    size_t off_featT  = (off_perm + (size_t)NPTS_TOT * 4 + 255) & ~(size_t)255;  // 102.4 MB
    size_t off_avg    = (off_featT + (size_t)NPTS_TOT * FF * 2 + 255) & ~(size_t)255;
    size_t needed     = off_avg + (size_t)SEGS * FF * 2;  // ~145 MB

    float* sums    = (float*)(ws + off_sums);
    int* rad_bits  = (int*)(ws + off_rad);
    int* counts    = (int*)(ws + off_counts);
    int* offsets   = (int*)(ws + off_offs);
    int* cursors   = (int*)(ws + off_curs);
    int* blocksums = (int*)(ws + off_bsums);
    int* blockoff  = (int*)(ws + off_boff);
    int* voxidx    = (int*)(ws + off_vox);
    int* rowvox    = (int*)(ws + off_rowv);
    int* perm      = (int*)(ws + off_perm);
    ushort* featT  = (ushort*)(ws + off_featT);
    ushort* avgS   = (ushort*)(ws + off_avg);

    bool fast = (ws_size >= needed);

    if (fast) {
        hipMemsetAsync(ws, 0, off_bsums, stream);  // sums/rad/counts/offsets(junk ok)/cursors
    } else {
        hipMemsetAsync(ws, 0, off_offs, stream);   // sums/rad/counts
        hipMemsetAsync(grid, 0, GRID_ELEMS * sizeof(float), stream);
    }

    k_sum_coords<<<BB * NB_STAT, 256, 0, stream>>>(coords, sums);
    k_radius<<<BB * NB_STAT, 256, 0, stream>>>(coords, sums, rad_bits);

    int pts_blocks = (NPTS_TOT + 255) / 256;
    k_voxelize<<<pts_blocks, 256, 0, stream>>>(coords, sums, rad_bits, norm_out, voxidx, counts);

    if (fast) {
        k_scan1<<<256, 256, 0, stream>>>(counts, offsets, blocksums);
        k_scan2<<<1, 256, 0, stream>>>(blocksums, blockoff);
        k_fillvox<<<(SEGS + 255) / 256, 256, 0, stream>>>(offsets, blockoff, counts, rowvox);
        k_rank<<<pts_blocks, 256, 0, stream>>>(voxidx, offsets, blockoff, cursors, perm);
        dim3 tgrid((NPTS + 63) / 64, BB);
        k_transpose<<<tgrid, 256, 0, stream>>>(features, featT);
        k_gather_lin<<<NWIN / 4, 256, 0, stream>>>(featT, perm, rowvox, counts, avgS);
        k_avg2grid<<<SEGS / 64, 256, 0, stream>>>(avgS, counts, grid);
    } else {
        size_t scatter_threads = (size_t)BB * FF * NPTS;
        int scatter_blocks = (int)((scatter_threads + 255) / 256);
        k_scatter<<<scatter_blocks, 256, 0, stream>>>(features, voxidx, grid);
        int norm_blocks = (int)((GRID_ELEMS + 255) / 256);
        k_normalize<<<norm_blocks, 256, 0, stream>>>(grid, counts);
    }
}

// Round 6
// 309.472 us; speedup vs baseline: 1.2711x; 1.2711x over previous
//
#include <hip/hip_runtime.h>
#include <hip/hip_bf16.h>

#define BB 8
#define FF 64
#define NPTS 100000
#define RES 32
#define R3 (RES*RES*RES)
#define EPSV 1e-6f
#define SEGS (BB*R3)            // 262144 voxel segments (2^18)
#define NPTS_TOT (BB*NPTS)      // 800000 points (= sorted rows)
#define NWIN (NPTS_TOT/64)      // 12500 gather windows (exact)

static constexpr size_t GRID_ELEMS = (size_t)BB * FF * R3;   // 16,777,216

__device__ __forceinline__ float bf16f(ushort u) {
    return __uint_as_float((unsigned)u << 16);
}
__device__ __forceinline__ ushort f2bf(float f) {
    __hip_bfloat16 h = __float2bfloat16(f);
    return *reinterpret_cast<ushort*>(&h);
}

// ---------------- Kernel A: per-batch coordinate sums ----------------
#define NB_STAT 64
__global__ void k_sum_coords(const float* __restrict__ coords, float* __restrict__ sums) {
    int b = blockIdx.x / NB_STAT;
    int chunk = blockIdx.x % NB_STAT;
    const float* cb = coords + (size_t)b * 3 * NPTS;
    float sx = 0.f, sy = 0.f, sz = 0.f;
    for (int i = chunk * blockDim.x + threadIdx.x; i < NPTS; i += NB_STAT * blockDim.x) {
        sx += cb[i];
        sy += cb[NPTS + i];
        sz += cb[2 * NPTS + i];
    }
    for (int off = 32; off; off >>= 1) {
        sx += __shfl_down(sx, off);
        sy += __shfl_down(sy, off);
        sz += __shfl_down(sz, off);
    }
    __shared__ float lsx[4], lsy[4], lsz[4];
    int lane = threadIdx.x & 63, wid = threadIdx.x >> 6;
    if (lane == 0) { lsx[wid] = sx; lsy[wid] = sy; lsz[wid] = sz; }
    __syncthreads();
    if (threadIdx.x == 0) {
        float tx = 0.f, ty = 0.f, tz = 0.f;
        for (int w = 0; w < 4; ++w) { tx += lsx[w]; ty += lsy[w]; tz += lsz[w]; }
        atomicAdd(&sums[b * 3 + 0], tx);
        atomicAdd(&sums[b * 3 + 1], ty);
        atomicAdd(&sums[b * 3 + 2], tz);
    }
}

// ---------------- Kernel B: per-batch max radius ----------------
__global__ void k_radius(const float* __restrict__ coords, const float* __restrict__ sums,
                         int* __restrict__ rad_bits) {
    int b = blockIdx.x / NB_STAT;
    int chunk = blockIdx.x % NB_STAT;
    const float* cb = coords + (size_t)b * 3 * NPTS;
    float mx = sums[b * 3 + 0] / (float)NPTS;
    float my = sums[b * 3 + 1] / (float)NPTS;
    float mz = sums[b * 3 + 2] / (float)NPTS;
    float mval = 0.f;
    for (int i = chunk * blockDim.x + threadIdx.x; i < NPTS; i += NB_STAT * blockDim.x) {
        float x = cb[i] - mx;
        float y = cb[NPTS + i] - my;
        float z = cb[2 * NPTS + i] - mz;
        float nrm = sqrtf(x * x + y * y + z * z);
        mval = fmaxf(mval, nrm);
    }
    for (int off = 32; off; off >>= 1) mval = fmaxf(mval, __shfl_down(mval, off));
    __shared__ float lm[4];
    int lane = threadIdx.x & 63, wid = threadIdx.x >> 6;
    if (lane == 0) lm[wid] = mval;
    __syncthreads();
    if (threadIdx.x == 0) {
        float t = fmaxf(fmaxf(lm[0], lm[1]), fmaxf(lm[2], lm[3]));
        atomicMax(&rad_bits[b], __float_as_int(t));  // norms >= 0: int order == float order
    }
}

// ---------------- Kernel C: per-point voxelize + norm_coords + counts ----------------
__global__ void k_voxelize(const float* __restrict__ coords, const float* __restrict__ sums,
                           const int* __restrict__ rad_bits, float* __restrict__ norm_out,
                           int* __restrict__ voxidx, int* __restrict__ counts) {
    int tid = blockIdx.x * blockDim.x + threadIdx.x;
    if (tid >= NPTS_TOT) return;
    int b = tid / NPTS, n = tid % NPTS;
    const float* cb = coords + (size_t)b * 3 * NPTS;
    float mx = sums[b * 3 + 0] / (float)NPTS;
    float my = sums[b * 3 + 1] / (float)NPTS;
    float mz = sums[b * 3 + 2] / (float)NPTS;
    float r = __int_as_float(rad_bits[b]);
    float d = 2.0f * r + EPSV;
    float x = (cb[n] - mx) / d + 0.5f;
    float y = (cb[NPTS + n] - my) / d + 0.5f;
    float z = (cb[2 * NPTS + n] - mz) / d + 0.5f;
    float nx = fminf(fmaxf(x * (float)RES, 0.0f), (float)(RES - 1));
    float ny = fminf(fmaxf(y * (float)RES, 0.0f), (float)(RES - 1));
    float nz = fminf(fmaxf(z * (float)RES, 0.0f), (float)(RES - 1));
    float* nb_ = norm_out + (size_t)b * 3 * NPTS;
    nb_[n] = nx;
    nb_[NPTS + n] = ny;
    nb_[2 * NPTS + n] = nz;
    int vx = (int)rintf(nx), vy = (int)rintf(ny), vz = (int)rintf(nz);
    int idx = (vx * RES + vy) * RES + vz;
    voxidx[tid] = idx;
    atomicAdd(&counts[b * R3 + idx], 1);
}

// ---------------- Scan: exclusive prefix sum over SEGS counts ----------------
__global__ void k_scan1(const int* __restrict__ counts, int* __restrict__ offsets,
                        int* __restrict__ blocksums) {
    int tid = threadIdx.x, bid = blockIdx.x;
    int base = bid * 1024 + tid * 4;
    int c0 = counts[base], c1 = counts[base + 1], c2 = counts[base + 2], c3 = counts[base + 3];
    int tot = c0 + c1 + c2 + c3;
    int lane = tid & 63, wid = tid >> 6;
    int v = tot;
    for (int off = 1; off < 64; off <<= 1) {
        int u = __shfl_up(v, off);
        if (lane >= off) v += u;
    }
    __shared__ int wtot[4];
    if (lane == 63) wtot[wid] = v;
    __syncthreads();
    int wof = 0;
    for (int w = 0; w < wid; ++w) wof += wtot[w];
    int ex = wof + v - tot;
    offsets[base] = ex;
    offsets[base + 1] = ex + c0;
    offsets[base + 2] = ex + c0 + c1;
    offsets[base + 3] = ex + c0 + c1 + c2;
    if (tid == 0) blocksums[bid] = wtot[0] + wtot[1] + wtot[2] + wtot[3];
}

__global__ void k_scan2(const int* __restrict__ blocksums, int* __restrict__ blockoff) {
    int tid = threadIdx.x;
    int c = blocksums[tid];
    int lane = tid & 63, wid = tid >> 6;
    int v = c;
    for (int off = 1; off < 64; off <<= 1) {
        int u = __shfl_up(v, off);
        if (lane >= off) v += u;
    }
    __shared__ int wtot[4];
    if (lane == 63) wtot[wid] = v;
    __syncthreads();
    int wof = 0;
    for (int w = 0; w < wid; ++w) wof += wtot[w];
    blockoff[tid] = wof + v - c;
}

// ---------------- Kernel C2: fill row->voxel map (sequential runs) ----------------
__global__ void k_fillvox(const int* __restrict__ offsets, const int* __restrict__ blockoff,
                          const int* __restrict__ counts, int* __restrict__ rowvox) {
    int bv = blockIdx.x * 256 + threadIdx.x;
    if (bv >= SEGS) return;
    int off = offsets[bv] + blockoff[bv >> 10];
    int cnt = counts[bv];
    for (int i = 0; i < cnt; ++i) rowvox[off + i] = bv;
}

// ---------------- Kernel C3: perm[dst] = global point row ----------------
__global__ void k_rank(const int* __restrict__ voxidx, const int* __restrict__ offsets,
                       const int* __restrict__ blockoff, int* __restrict__ cursors,
                       int* __restrict__ perm) {
    int g = blockIdx.x * 256 + threadIdx.x;
    if (g >= NPTS_TOT) return;
    int b = g / NPTS;
    int bv = b * R3 + voxidx[g];
    int r = atomicAdd(&cursors[bv], 1);
    perm[offsets[bv] + blockoff[bv >> 10] + r] = g;
}

// ---------------- Kernel D: plain transpose features[B,F,N] -> featT[B*N][64] bf16 ------
__global__ void k_transpose(const float* __restrict__ features, ushort* __restrict__ featT) {
    __shared__ float tileF[64][65];
    int b = blockIdx.y;
    int n0 = blockIdx.x * 64;
    int tid = threadIdx.x, lane = tid & 63, wid = tid >> 6;

    for (int f = wid; f < 64; f += 4) {
        int n = n0 + lane;
        tileF[f][lane] = (n < NPTS) ? features[((size_t)b * FF + f) * NPTS + n] : 0.f;
    }
    __syncthreads();
    size_t g0 = (size_t)b * NPTS + n0;
    int half = lane >> 5;            // 0/1: which of 2 rows this instruction covers
    int f0 = (lane & 31) * 2;        // feature pair
#pragma unroll
    for (int k = 0; k < 8; ++k) {
        int p = wid * 16 + k * 2 + half;
        if (n0 + p < NPTS) {
            unsigned val = (unsigned)f2bf(tileF[f0][p]) | ((unsigned)f2bf(tileF[f0 + 1][p]) << 16);
            ((unsigned*)(featT + ((g0 + p) << 6)))[lane & 31] = val;   // 256B/instr, sequential
        }
    }
}

// ---------------- Kernel E1: linear segmented gather (perm-indirect reads) --------------
// One wave per 64 consecutive sorted rows. Stage window via featT[perm[r]] (128B rows,
// L3-resident) into LDS. Overhang of the window-final segment is processed in 64-row
// chunks with the SAME wave-parallel staging (8 independent 8-row reads per chunk) --
// no latency-chained scalar walks.
__global__ void k_gather_lin(const ushort* __restrict__ featT,
                             const int* __restrict__ perm,
                             const int* __restrict__ rowvox,
                             const int* __restrict__ counts,
                             ushort* __restrict__ avgS) {
    __shared__ ushort tile[4][4096];   // 8KB per wave
    int wid = threadIdx.x >> 6, lane = threadIdx.x & 63;
    int w = blockIdx.x * 4 + wid;      // window id [0, NWIN)
    int r0 = w * 64;

    int pr = perm[r0 + lane];          // point row for my sorted row
    int myv = rowvox[r0 + lane];

    // stage window: 8 instrs, each reads 8 scattered 128B rows (8 lanes/row, 16B/lane)
    uint4 t[8];
    uint4* ldst = (uint4*)tile[wid];
#pragma unroll
    for (int j = 0; j < 8; ++j) {
        int row = j * 8 + (lane >> 3);
        int pi = __shfl(pr, row);
        t[j] = ((const uint4*)(featT + ((size_t)pi << 6)))[lane & 7];
    }
#pragma unroll
    for (int j = 0; j < 8; ++j) ldst[j * 64 + lane] = t[j];   // contiguous: lane*16B

    int prevv = __shfl_up(myv, 1);
    if (lane == 0) prevv = (r0 > 0) ? rowvox[r0 - 1] : -1;
    unsigned long long flags = __ballot(myv != prevv);

    while (flags) {
        int s = (int)__ffsll(flags) - 1;
        flags &= flags - 1;
        int bv = __shfl(myv, s);
        int cnt = flags ? ((int)__ffsll(flags) - 1 - s) : counts[bv];
        int inwin = min(cnt, 64 - s);
        float acc = 0.f;
        for (int i = 0; i < inwin; ++i) acc += bf16f(tile[wid][(s + i) * 64 + lane]);
        // Overhang: only possible for the window's LAST segment (contiguity), so the
        // tile is free for reuse. Chunked wave-parallel staging, one round-trip / 64 rows.
        int done = inwin;
        int rbase = r0 + 64;
        while (done < cnt) {
            int chunk = min(64, cnt - done);
            int pi_l = perm[min(rbase + lane, NPTS_TOT - 1)];  // rows past segment: clamped, ignored
#pragma unroll
            for (int j = 0; j < 8; ++j) {
                int row = j * 8 + (lane >> 3);
                int pi = __shfl(pi_l, row);
                t[j] = ((const uint4*)(featT + ((size_t)pi << 6)))[lane & 7];
            }
#pragma unroll
            for (int j = 0; j < 8; ++j) ldst[j * 64 + lane] = t[j];
            for (int i = 0; i < chunk; ++i) acc += bf16f(tile[wid][i * 64 + lane]);
            done += chunk;
            rbase += 64;
        }
        avgS[(size_t)bv * 64 + lane] = f2bf(acc / (float)cnt);
    }
}

// ---------------- Kernel E2: avgS [BV][F] bf16 -> grid [B][F][V] f32 (LDS transpose) ----
__global__ void k_avg2grid(const ushort* __restrict__ avgS, const int* __restrict__ counts,
                           float* __restrict__ grid) {
    __shared__ float tile[64][65];
    int bv0 = blockIdx.x * 64;
    int lane = threadIdx.x & 63, wid = threadIdx.x >> 6;
    for (int p = wid; p < 64; p += 4) {
        int cnt = counts[bv0 + p];
        tile[p][lane] = (cnt > 0) ? bf16f(avgS[(size_t)(bv0 + p) * 64 + lane]) : 0.f;
    }
    __syncthreads();
    int b = bv0 >> 15;          // /R3
    int v0 = bv0 & (R3 - 1);
    for (int f = wid; f < 64; f += 4) {
        grid[((size_t)b * FF + f) * R3 + v0 + lane] = tile[lane][f];
    }
}

// ---------------- Fallback path (atomic scatter), used if ws too small ----------------
__global__ void k_scatter(const float* __restrict__ features, const int* __restrict__ voxidx,
                          float* __restrict__ grid) {
    size_t tid = (size_t)blockIdx.x * blockDim.x + threadIdx.x;
    if (tid >= (size_t)BB * FF * NPTS) return;
    int n = (int)(tid % NPTS);
    int bf = (int)(tid / NPTS);
    int b = bf >> 6;
    int idx = voxidx[(size_t)b * NPTS + n];
    atomicAdd(&grid[(size_t)bf * R3 + idx], features[tid]);
}

__global__ void k_normalize(float* __restrict__ grid, const int* __restrict__ counts) {
    size_t tid = (size_t)blockIdx.x * blockDim.x + threadIdx.x;
    if (tid >= GRID_ELEMS) return;
    int v = (int)(tid % R3);
    int bf = (int)(tid / R3);
    int b = bf >> 6;
    float c = (float)counts[b * R3 + v];
    grid[tid] = grid[tid] / fmaxf(c, 1.0f);
}

extern "C" void kernel_launch(void* const* d_in, const int* in_sizes, int n_in,
                              void* d_out, int out_size, void* d_ws, size_t ws_size,
                              hipStream_t stream) {
    const float* features = (const float*)d_in[0];
    const float* coords = (const float*)d_in[1];
    float* out = (float*)d_out;
    float* grid = out;                      // [B,F,R,R,R]
    float* norm_out = out + GRID_ELEMS;     // [B,3,N]

    char* ws = (char*)d_ws;
    size_t off_sums   = 0;                               // 24 floats
    size_t off_rad    = 128;                             // 8 ints
    size_t off_counts = 256;                             // SEGS ints (1 MB)
    size_t off_offs   = off_counts + (size_t)SEGS * 4;   // 1 MB
    size_t off_curs   = off_offs + (size_t)SEGS * 4;     // 1 MB
    size_t off_bsums  = off_curs + (size_t)SEGS * 4;
    size_t off_boff   = off_bsums + 256 * 4;
    size_t off_vox    = off_boff + 256 * 4;              // 3.2 MB
    size_t off_rowv   = off_vox + (size_t)NPTS_TOT * 4;  // 3.2 MB
    size_t off_perm   = off_rowv + (size_t)NPTS_TOT * 4; // 3.2 MB
    size_t off_featT  = (off_perm + (size_t)NPTS_TOT * 4 + 255) & ~(size_t)255;  // 102.4 MB
    size_t off_avg    = (off_featT + (size_t)NPTS_TOT * FF * 2 + 255) & ~(size_t)255;
    size_t needed     = off_avg + (size_t)SEGS * FF * 2;  // ~145 MB

    float* sums    = (float*)(ws + off_sums);
    int* rad_bits  = (int*)(ws + off_rad);
    int* counts    = (int*)(ws + off_counts);
    int* offsets   = (int*)(ws + off_offs);
    int* cursors   = (int*)(ws + off_curs);
    int* blocksums = (int*)(ws + off_bsums);
    int* blockoff  = (int*)(ws + off_boff);
    int* voxidx    = (int*)(ws + off_vox);
    int* rowvox    = (int*)(ws + off_rowv);
    int* perm      = (int*)(ws + off_perm);
    ushort* featT  = (ushort*)(ws + off_featT);
    ushort* avgS   = (ushort*)(ws + off_avg);

    bool fast = (ws_size >= needed);

    if (fast) {
        hipMemsetAsync(ws, 0, off_bsums, stream);  // sums/rad/counts/offsets(junk ok)/cursors
    } else {
        hipMemsetAsync(ws, 0, off_offs, stream);   // sums/rad/counts
        hipMemsetAsync(grid, 0, GRID_ELEMS * sizeof(float), stream);
    }

    k_sum_coords<<<BB * NB_STAT, 256, 0, stream>>>(coords, sums);
    k_radius<<<BB * NB_STAT, 256, 0, stream>>>(coords, sums, rad_bits);

    int pts_blocks = (NPTS_TOT + 255) / 256;
    k_voxelize<<<pts_blocks, 256, 0, stream>>>(coords, sums, rad_bits, norm_out, voxidx, counts);

    if (fast) {
        k_scan1<<<256, 256, 0, stream>>>(counts, offsets, blocksums);
        k_scan2<<<1, 256, 0, stream>>>(blocksums, blockoff);
        k_fillvox<<<(SEGS + 255) / 256, 256, 0, stream>>>(offsets, blockoff, counts, rowvox);
        k_rank<<<pts_blocks, 256, 0, stream>>>(voxidx, offsets, blockoff, cursors, perm);
        dim3 tgrid((NPTS + 63) / 64, BB);
        k_transpose<<<tgrid, 256, 0, stream>>>(features, featT);
        k_gather_lin<<<NWIN / 4, 256, 0, stream>>>(featT, perm, rowvox, counts, avgS);
        k_avg2grid<<<SEGS / 64, 256, 0, stream>>>(avgS, counts, grid);
    } else {
        size_t scatter_threads = (size_t)BB * FF * NPTS;
        int scatter_blocks = (int)((scatter_threads + 255) / 256);
        k_scatter<<<scatter_blocks, 256, 0, stream>>>(features, voxidx, grid);
        int norm_blocks = (int)((GRID_ELEMS + 255) / 256);
        k_normalize<<<norm_blocks, 256, 0, stream>>>(grid, counts);
    }
}

// Round 7
// 308.228 us; speedup vs baseline: 1.2763x; 1.0040x over previous
//
#include <hip/hip_runtime.h>
#include <hip/hip_bf16.h>

#define BB 8
#define FF 64
#define NPTS 100000
#define RES 32
#define R3 (RES*RES*RES)
#define EPSV 1e-6f
#define SEGS (BB*R3)            // 262144 voxel segments (2^18)
#define NPTS_TOT (BB*NPTS)      // 800000 points (= sorted rows)
#define NWIN (NPTS_TOT/64)      // 12500 gather windows (exact)

static constexpr size_t GRID_ELEMS = (size_t)BB * FF * R3;   // 16,777,216

__device__ __forceinline__ float bf16f(ushort u) {
    return __uint_as_float((unsigned)u << 16);
}
__device__ __forceinline__ ushort f2bf(float f) {
    __hip_bfloat16 h = __float2bfloat16(f);
    return *reinterpret_cast<ushort*>(&h);
}

// ---------------- Kernel Z: fast zero (replaces pathological rocclr fill) ----------------
// In-graph hipMemsetAsync ran fillBufferAligned at 26 GB/s (119us for 3MB). This does
// the same zeroing with uint4 stores in ~1us.
__global__ void k_zero(uint4* __restrict__ p, int n16) {
    int i = blockIdx.x * 256 + threadIdx.x;
    if (i < n16) p[i] = make_uint4(0u, 0u, 0u, 0u);
}

// ---------------- Kernel A: per-batch coordinate sums ----------------
#define NB_STAT 64
__global__ void k_sum_coords(const float* __restrict__ coords, float* __restrict__ sums) {
    int b = blockIdx.x / NB_STAT;
    int chunk = blockIdx.x % NB_STAT;
    const float* cb = coords + (size_t)b * 3 * NPTS;
    float sx = 0.f, sy = 0.f, sz = 0.f;
    for (int i = chunk * blockDim.x + threadIdx.x; i < NPTS; i += NB_STAT * blockDim.x) {
        sx += cb[i];
        sy += cb[NPTS + i];
        sz += cb[2 * NPTS + i];
    }
    for (int off = 32; off; off >>= 1) {
        sx += __shfl_down(sx, off);
        sy += __shfl_down(sy, off);
        sz += __shfl_down(sz, off);
    }
    __shared__ float lsx[4], lsy[4], lsz[4];
    int lane = threadIdx.x & 63, wid = threadIdx.x >> 6;
    if (lane == 0) { lsx[wid] = sx; lsy[wid] = sy; lsz[wid] = sz; }
    __syncthreads();
    if (threadIdx.x == 0) {
        float tx = 0.f, ty = 0.f, tz = 0.f;
        for (int w = 0; w < 4; ++w) { tx += lsx[w]; ty += lsy[w]; tz += lsz[w]; }
        atomicAdd(&sums[b * 3 + 0], tx);
        atomicAdd(&sums[b * 3 + 1], ty);
        atomicAdd(&sums[b * 3 + 2], tz);
    }
}

// ---------------- Kernel B: per-batch max radius ----------------
__global__ void k_radius(const float* __restrict__ coords, const float* __restrict__ sums,
                         int* __restrict__ rad_bits) {
    int b = blockIdx.x / NB_STAT;
    int chunk = blockIdx.x % NB_STAT;
    const float* cb = coords + (size_t)b * 3 * NPTS;
    float mx = sums[b * 3 + 0] / (float)NPTS;
    float my = sums[b * 3 + 1] / (float)NPTS;
    float mz = sums[b * 3 + 2] / (float)NPTS;
    float mval = 0.f;
    for (int i = chunk * blockDim.x + threadIdx.x; i < NPTS; i += NB_STAT * blockDim.x) {
        float x = cb[i] - mx;
        float y = cb[NPTS + i] - my;
        float z = cb[2 * NPTS + i] - mz;
        float nrm = sqrtf(x * x + y * y + z * z);
        mval = fmaxf(mval, nrm);
    }
    for (int off = 32; off; off >>= 1) mval = fmaxf(mval, __shfl_down(mval, off));
    __shared__ float lm[4];
    int lane = threadIdx.x & 63, wid = threadIdx.x >> 6;
    if (lane == 0) lm[wid] = mval;
    __syncthreads();
    if (threadIdx.x == 0) {
        float t = fmaxf(fmaxf(lm[0], lm[1]), fmaxf(lm[2], lm[3]));
        atomicMax(&rad_bits[b], __float_as_int(t));  // norms >= 0: int order == float order
    }
}

// ---------------- Kernel C: per-point voxelize + norm_coords + counts ----------------
__global__ void k_voxelize(const float* __restrict__ coords, const float* __restrict__ sums,
                           const int* __restrict__ rad_bits, float* __restrict__ norm_out,
                           int* __restrict__ voxidx, int* __restrict__ counts) {
    int tid = blockIdx.x * blockDim.x + threadIdx.x;
    if (tid >= NPTS_TOT) return;
    int b = tid / NPTS, n = tid % NPTS;
    const float* cb = coords + (size_t)b * 3 * NPTS;
    float mx = sums[b * 3 + 0] / (float)NPTS;
    float my = sums[b * 3 + 1] / (float)NPTS;
    float mz = sums[b * 3 + 2] / (float)NPTS;
    float r = __int_as_float(rad_bits[b]);
    float d = 2.0f * r + EPSV;
    float x = (cb[n] - mx) / d + 0.5f;
    float y = (cb[NPTS + n] - my) / d + 0.5f;
    float z = (cb[2 * NPTS + n] - mz) / d + 0.5f;
    float nx = fminf(fmaxf(x * (float)RES, 0.0f), (float)(RES - 1));
    float ny = fminf(fmaxf(y * (float)RES, 0.0f), (float)(RES - 1));
    float nz = fminf(fmaxf(z * (float)RES, 0.0f), (float)(RES - 1));
    float* nb_ = norm_out + (size_t)b * 3 * NPTS;
    nb_[n] = nx;
    nb_[NPTS + n] = ny;
    nb_[2 * NPTS + n] = nz;
    int vx = (int)rintf(nx), vy = (int)rintf(ny), vz = (int)rintf(nz);
    int idx = (vx * RES + vy) * RES + vz;
    voxidx[tid] = idx;
    atomicAdd(&counts[b * R3 + idx], 1);
}

// ---------------- Scan: exclusive prefix sum over SEGS counts ----------------
__global__ void k_scan1(const int* __restrict__ counts, int* __restrict__ offsets,
                        int* __restrict__ blocksums) {
    int tid = threadIdx.x, bid = blockIdx.x;
    int base = bid * 1024 + tid * 4;
    int c0 = counts[base], c1 = counts[base + 1], c2 = counts[base + 2], c3 = counts[base + 3];
    int tot = c0 + c1 + c2 + c3;
    int lane = tid & 63, wid = tid >> 6;
    int v = tot;
    for (int off = 1; off < 64; off <<= 1) {
        int u = __shfl_up(v, off);
        if (lane >= off) v += u;
    }
    __shared__ int wtot[4];
    if (lane == 63) wtot[wid] = v;
    __syncthreads();
    int wof = 0;
    for (int w = 0; w < wid; ++w) wof += wtot[w];
    int ex = wof + v - tot;
    offsets[base] = ex;
    offsets[base + 1] = ex + c0;
    offsets[base + 2] = ex + c0 + c1;
    offsets[base + 3] = ex + c0 + c1 + c2;
    if (tid == 0) blocksums[bid] = wtot[0] + wtot[1] + wtot[2] + wtot[3];
}

__global__ void k_scan2(const int* __restrict__ blocksums, int* __restrict__ blockoff) {
    int tid = threadIdx.x;
    int c = blocksums[tid];
    int lane = tid & 63, wid = tid >> 6;
    int v = c;
    for (int off = 1; off < 64; off <<= 1) {
        int u = __shfl_up(v, off);
        if (lane >= off) v += u;
    }
    __shared__ int wtot[4];
    if (lane == 63) wtot[wid] = v;
    __syncthreads();
    int wof = 0;
    for (int w = 0; w < wid; ++w) wof += wtot[w];
    blockoff[tid] = wof + v - c;
}

// ---------------- Kernel C2: fill row->voxel map (sequential runs) ----------------
__global__ void k_fillvox(const int* __restrict__ offsets, const int* __restrict__ blockoff,
                          const int* __restrict__ counts, int* __restrict__ rowvox) {
    int bv = blockIdx.x * 256 + threadIdx.x;
    if (bv >= SEGS) return;
    int off = offsets[bv] + blockoff[bv >> 10];
    int cnt = counts[bv];
    for (int i = 0; i < cnt; ++i) rowvox[off + i] = bv;
}

// ---------------- Kernel C3: perm[dst] = global point row ----------------
__global__ void k_rank(const int* __restrict__ voxidx, const int* __restrict__ offsets,
                       const int* __restrict__ blockoff, int* __restrict__ cursors,
                       int* __restrict__ perm) {
    int g = blockIdx.x * 256 + threadIdx.x;
    if (g >= NPTS_TOT) return;
    int b = g / NPTS;
    int bv = b * R3 + voxidx[g];
    int r = atomicAdd(&cursors[bv], 1);
    perm[offsets[bv] + blockoff[bv >> 10] + r] = g;
}

// ---------------- Kernel D: plain transpose features[B,F,N] -> featT[B*N][64] bf16 ------
__global__ void k_transpose(const float* __restrict__ features, ushort* __restrict__ featT) {
    __shared__ float tileF[64][65];
    int b = blockIdx.y;
    int n0 = blockIdx.x * 64;
    int tid = threadIdx.x, lane = tid & 63, wid = tid >> 6;

    for (int f = wid; f < 64; f += 4) {
        int n = n0 + lane;
        tileF[f][lane] = (n < NPTS) ? features[((size_t)b * FF + f) * NPTS + n] : 0.f;
    }
    __syncthreads();
    size_t g0 = (size_t)b * NPTS + n0;
    int half = lane >> 5;            // 0/1: which of 2 rows this instruction covers
    int f0 = (lane & 31) * 2;        // feature pair
#pragma unroll
    for (int k = 0; k < 8; ++k) {
        int p = wid * 16 + k * 2 + half;
        if (n0 + p < NPTS) {
            unsigned val = (unsigned)f2bf(tileF[f0][p]) | ((unsigned)f2bf(tileF[f0 + 1][p]) << 16);
            ((unsigned*)(featT + ((g0 + p) << 6)))[lane & 31] = val;   // 256B/instr, sequential
        }
    }
}

// ---------------- Kernel E1: linear segmented gather (perm-indirect reads) --------------
// One wave per 64 consecutive sorted rows. Stage window via featT[perm[r]] (128B rows,
// L3-resident) into LDS. Overhang of the window-final segment is processed in 64-row
// chunks with the SAME wave-parallel staging (8 independent 8-row reads per chunk) --
// no latency-chained scalar walks.
__global__ void k_gather_lin(const ushort* __restrict__ featT,
                             const int* __restrict__ perm,
                             const int* __restrict__ rowvox,
                             const int* __restrict__ counts,
                             ushort* __restrict__ avgS) {
    __shared__ ushort tile[4][4096];   // 8KB per wave
    int wid = threadIdx.x >> 6, lane = threadIdx.x & 63;
    int w = blockIdx.x * 4 + wid;      // window id [0, NWIN)
    int r0 = w * 64;

    int pr = perm[r0 + lane];          // point row for my sorted row
    int myv = rowvox[r0 + lane];

    // stage window: 8 instrs, each reads 8 scattered 128B rows (8 lanes/row, 16B/lane)
    uint4 t[8];
    uint4* ldst = (uint4*)tile[wid];
#pragma unroll
    for (int j = 0; j < 8; ++j) {
        int row = j * 8 + (lane >> 3);
        int pi = __shfl(pr, row);
        t[j] = ((const uint4*)(featT + ((size_t)pi << 6)))[lane & 7];
    }
#pragma unroll
    for (int j = 0; j < 8; ++j) ldst[j * 64 + lane] = t[j];   // contiguous: lane*16B

    int prevv = __shfl_up(myv, 1);
    if (lane == 0) prevv = (r0 > 0) ? rowvox[r0 - 1] : -1;
    unsigned long long flags = __ballot(myv != prevv);

    while (flags) {
        int s = (int)__ffsll(flags) - 1;
        flags &= flags - 1;
        int bv = __shfl(myv, s);
        int cnt = flags ? ((int)__ffsll(flags) - 1 - s) : counts[bv];
        int inwin = min(cnt, 64 - s);
        float acc = 0.f;
        for (int i = 0; i < inwin; ++i) acc += bf16f(tile[wid][(s + i) * 64 + lane]);
        // Overhang: only possible for the window's LAST segment (contiguity), so the
        // tile is free for reuse. Chunked wave-parallel staging, one round-trip / 64 rows.
        int done = inwin;
        int rbase = r0 + 64;
        while (done < cnt) {
            int chunk = min(64, cnt - done);
            int pi_l = perm[min(rbase + lane, NPTS_TOT - 1)];  // rows past segment: clamped, ignored
#pragma unroll
            for (int j = 0; j < 8; ++j) {
                int row = j * 8 + (lane >> 3);
                int pi = __shfl(pi_l, row);
                t[j] = ((const uint4*)(featT + ((size_t)pi << 6)))[lane & 7];
            }
#pragma unroll
            for (int j = 0; j < 8; ++j) ldst[j * 64 + lane] = t[j];
            for (int i = 0; i < chunk; ++i) acc += bf16f(tile[wid][i * 64 + lane]);
            done += chunk;
            rbase += 64;
        }
        avgS[(size_t)bv * 64 + lane] = f2bf(acc / (float)cnt);
    }
}

// ---------------- Kernel E2: avgS [BV][F] bf16 -> grid [B][F][V] f32 (LDS transpose) ----
__global__ void k_avg2grid(const ushort* __restrict__ avgS, const int* __restrict__ counts,
                           float* __restrict__ grid) {
    __shared__ float tile[64][65];
    int bv0 = blockIdx.x * 64;
    int lane = threadIdx.x & 63, wid = threadIdx.x >> 6;
    for (int p = wid; p < 64; p += 4) {
        int cnt = counts[bv0 + p];
        tile[p][lane] = (cnt > 0) ? bf16f(avgS[(size_t)(bv0 + p) * 64 + lane]) : 0.f;
    }
    __syncthreads();
    int b = bv0 >> 15;          // /R3
    int v0 = bv0 & (R3 - 1);
    for (int f = wid; f < 64; f += 4) {
        grid[((size_t)b * FF + f) * R3 + v0 + lane] = tile[lane][f];
    }
}

// ---------------- Fallback path (atomic scatter), used if ws too small ----------------
__global__ void k_scatter(const float* __restrict__ features, const int* __restrict__ voxidx,
                          float* __restrict__ grid) {
    size_t tid = (size_t)blockIdx.x * blockDim.x + threadIdx.x;
    if (tid >= (size_t)BB * FF * NPTS) return;
    int n = (int)(tid % NPTS);
    int bf = (int)(tid / NPTS);
    int b = bf >> 6;
    int idx = voxidx[(size_t)b * NPTS + n];
    atomicAdd(&grid[(size_t)bf * R3 + idx], features[tid]);
}

__global__ void k_normalize(float* __restrict__ grid, const int* __restrict__ counts) {
    size_t tid = (size_t)blockIdx.x * blockDim.x + threadIdx.x;
    if (tid >= GRID_ELEMS) return;
    int v = (int)(tid % R3);
    int bf = (int)(tid / R3);
    int b = bf >> 6;
    float c = (float)counts[b * R3 + v];
    grid[tid] = grid[tid] / fmaxf(c, 1.0f);
}

extern "C" void kernel_launch(void* const* d_in, const int* in_sizes, int n_in,
                              void* d_out, int out_size, void* d_ws, size_t ws_size,
                              hipStream_t stream) {
    const float* features = (const float*)d_in[0];
    const float* coords = (const float*)d_in[1];
    float* out = (float*)d_out;
    float* grid = out;                      // [B,F,R,R,R]
    float* norm_out = out + GRID_ELEMS;     // [B,3,N]

    char* ws = (char*)d_ws;
    size_t off_sums   = 0;                               // 24 floats
    size_t off_rad    = 128;                             // 8 ints
    size_t off_counts = 256;                             // SEGS ints (1 MB)
    size_t off_offs   = off_counts + (size_t)SEGS * 4;   // 1 MB
    size_t off_curs   = off_offs + (size_t)SEGS * 4;     // 1 MB
    size_t off_bsums  = off_curs + (size_t)SEGS * 4;
    size_t off_boff   = off_bsums + 256 * 4;
    size_t off_vox    = off_boff + 256 * 4;              // 3.2 MB
    size_t off_rowv   = off_vox + (size_t)NPTS_TOT * 4;  // 3.2 MB
    size_t off_perm   = off_rowv + (size_t)NPTS_TOT * 4; // 3.2 MB
    size_t off_featT  = (off_perm + (size_t)NPTS_TOT * 4 + 255) & ~(size_t)255;  // 102.4 MB
    size_t off_avg    = (off_featT + (size_t)NPTS_TOT * FF * 2 + 255) & ~(size_t)255;
    size_t needed     = off_avg + (size_t)SEGS * FF * 2;  // ~145 MB

    float* sums    = (float*)(ws + off_sums);
    int* rad_bits  = (int*)(ws + off_rad);
    int* counts    = (int*)(ws + off_counts);
    int* offsets   = (int*)(ws + off_offs);
    int* cursors   = (int*)(ws + off_curs);
    int* blocksums = (int*)(ws + off_bsums);
    int* blockoff  = (int*)(ws + off_boff);
    int* voxidx    = (int*)(ws + off_vox);
    int* rowvox    = (int*)(ws + off_rowv);
    int* perm      = (int*)(ws + off_perm);
    ushort* featT  = (ushort*)(ws + off_featT);
    ushort* avgS   = (ushort*)(ws + off_avg);

    bool fast = (ws_size >= needed);

    if (fast) {
        // zero sums/rad/counts/(offsets: junk ok)/cursors with uint4 stores (~1us);
        // the in-graph hipMemsetAsync ran a 26 GB/s fill kernel costing ~119us.
        int n16 = (int)(off_bsums / 16);
        k_zero<<<(n16 + 255) / 256, 256, 0, stream>>>((uint4*)ws, n16);
    } else {
        hipMemsetAsync(ws, 0, off_offs, stream);   // sums/rad/counts
        hipMemsetAsync(grid, 0, GRID_ELEMS * sizeof(float), stream);
    }

    k_sum_coords<<<BB * NB_STAT, 256, 0, stream>>>(coords, sums);
    k_radius<<<BB * NB_STAT, 256, 0, stream>>>(coords, sums, rad_bits);

    int pts_blocks = (NPTS_TOT + 255) / 256;
    k_voxelize<<<pts_blocks, 256, 0, stream>>>(coords, sums, rad_bits, norm_out, voxidx, counts);

    if (fast) {
        k_scan1<<<256, 256, 0, stream>>>(counts, offsets, blocksums);
        k_scan2<<<1, 256, 0, stream>>>(blocksums, blockoff);
        k_fillvox<<<(SEGS + 255) / 256, 256, 0, stream>>>(offsets, blockoff, counts, rowvox);
        k_rank<<<pts_blocks, 256, 0, stream>>>(voxidx, offsets, blockoff, cursors, perm);
        dim3 tgrid((NPTS + 63) / 64, BB);
        k_transpose<<<tgrid, 256, 0, stream>>>(features, featT);
        k_gather_lin<<<NWIN / 4, 256, 0, stream>>>(featT, perm, rowvox, counts, avgS);
        k_avg2grid<<<SEGS / 64, 256, 0, stream>>>(avgS, counts, grid);
    } else {
        size_t scatter_threads = (size_t)BB * FF * NPTS;
        int scatter_blocks = (int)((scatter_threads + 255) / 256);
        k_scatter<<<scatter_blocks, 256, 0, stream>>>(features, voxidx, grid);
        int norm_blocks = (int)((GRID_ELEMS + 255) / 256);
        k_normalize<<<norm_blocks, 256, 0, stream>>>(grid, counts);
    }
}